// Round 1
// baseline (439.724 us; speedup 1.0000x reference)
//
#include <hip/hip_runtime.h>
#include <stdint.h>

#define BATCH   16
#define NANCH   25200
#define NCLS    80
#define REC     85
#define MAXDET  300
#define TMAX    50
#define CAP     8192
#define NBUCKET 2048
#define FINCAP  1024

// output offsets (floats)
#define OFF_PB 0
#define OFF_PS 19200
#define OFF_PL 24000
#define OFF_PK 28800
#define OFF_TB 33600
#define OFF_TS 36800
#define OFF_TL 37600
#define OFF_TV 38400

__device__ __forceinline__ float opaque_f(float x) { asm volatile("" : "+v"(x)); return x; }

// ---------------- Kernel A: score + compact candidates ----------------
// 128 anchors per block, staged through LDS with coalesced float4 loads.
__global__ __launch_bounds__(128) void kA(const float* __restrict__ logits,
                                          int* __restrict__ cnt,
                                          unsigned long long* __restrict__ keys) {
    __shared__ float s[128 * REC];   // 43520 B
    const int tid = threadIdx.x;
    const float4* g4 = (const float4*)(logits + (long long)blockIdx.x * (128 * REC));
    float4* s4 = (float4*)s;
#pragma unroll
    for (int i = 0; i < 22; ++i) {
        int idx = tid + i * 128;
        if (idx < (128 * REC / 4)) s4[idx] = g4[idx];
    }
    __syncthreads();
    const int base = tid * REC;
    float obj  = s[base + 4];
    float best = s[base + 5];
#pragma unroll
    for (int c = 1; c < NCLS; ++c) best = fmaxf(best, s[base + 5 + c]);
    float conf = obj * best;                 // exact: single multiply
    if (conf > 0.8f) {
        int g = blockIdx.x * 128 + tid;
        int b = g / NANCH;
        int n = g - b * NANCH;
        int pos = atomicAdd(cnt + b * 16, 1);   // counters padded to 64B
        if (pos < CAP) {
            unsigned long long key =
                ((unsigned long long)__float_as_uint(conf) << 32) |
                (unsigned)(0xFFFFFFFFu - (unsigned)n);   // ties: smaller idx sorts first
            keys[(size_t)b * CAP + pos] = key;
        }
    }
}

// ---------------- Kernel B: radix-select + bitonic top-300 ----------------
__global__ __launch_bounds__(1024) void kB(const int* __restrict__ cnt,
                                           const unsigned long long* __restrict__ keys,
                                           unsigned long long* __restrict__ topkeys) {
    __shared__ unsigned hist[NBUCKET];
    __shared__ unsigned long long fin[FINCAP];
    __shared__ int sTb, sCnt;
    const int b = blockIdx.x;
    const int tid = threadIdx.x;
    int cb = cnt[b * 16]; if (cb > CAP) cb = CAP;
    const unsigned long long* kb = keys + (size_t)b * CAP;

    for (int i = tid; i < NBUCKET; i += 1024) hist[i] = 0u;
    if (tid == 0) sCnt = 0;
    __syncthreads();
    for (int i = tid; i < cb; i += 1024) {
        unsigned bits = (unsigned)(kb[i] >> 32);      // conf bits, > 0x3F4CCCCD
        unsigned bk = (bits - 0x3F4CCCCDu) >> 11;     // linear in value (one binade)
        if (bk > NBUCKET - 1u) bk = NBUCKET - 1u;
        atomicAdd(&hist[bk], 1u);
    }
    __syncthreads();
    if (tid == 0) {
        int c = 0, tb = 0;
        for (int bk = NBUCKET - 1; bk >= 0; --bk) {
            c += (int)hist[bk];
            if (c >= MAXDET) { tb = bk; break; }
        }
        sTb = tb;
    }
    __syncthreads();
    int tb = sTb;
    for (int i = tid; i < cb; i += 1024) {
        unsigned long long k = kb[i];
        unsigned bits = (unsigned)(k >> 32);
        unsigned bk = (bits - 0x3F4CCCCDu) >> 11;
        if (bk > NBUCKET - 1u) bk = NBUCKET - 1u;
        if ((int)bk >= tb) {
            int p = atomicAdd(&sCnt, 1);
            if (p < FINCAP) fin[p] = k;
        }
    }
    __syncthreads();
    int fc = sCnt; if (fc > FINCAP) fc = FINCAP;
    for (int i = tid; i < FINCAP; i += 1024) if (i >= fc) fin[i] = 0ull;
    // bitonic sort descending (keys unique -> deterministic)
    for (unsigned k = 2; k <= FINCAP; k <<= 1) {
        for (unsigned j = k >> 1; j > 0; j >>= 1) {
            __syncthreads();
            unsigned t = tid;
            unsigned ixj = t ^ j;
            if (ixj > t && t < FINCAP) {
                unsigned long long a = fin[t], c2 = fin[ixj];
                bool desc = ((t & k) == 0u);
                bool sw = desc ? (a < c2) : (a > c2);
                if (sw) { fin[t] = c2; fin[ixj] = a; }
            }
        }
    }
    __syncthreads();
    if (tid < MAXDET) topkeys[b * MAXDET + tid] = fin[tid];
}

// ---------------- Kernel C: gather + NMS + outputs ----------------
__global__ __launch_bounds__(512) void kC(const float* __restrict__ logits,
                                          const unsigned long long* __restrict__ topkeys,
                                          float* __restrict__ out) {
    __shared__ float bx1[MAXDET], by1[MAXDET], bx2[MAXDET], by2[MAXDET];
    __shared__ unsigned supp[MAXDET * 10];   // 300 rows x 320 bits
    __shared__ unsigned keepw[10];
    const int b = blockIdx.x;
    const int tid = threadIdx.x;
    for (int i = tid; i < MAXDET * 10; i += 512) supp[i] = 0u;
    if (tid < MAXDET) {
        unsigned long long key = topkeys[b * MAXDET + tid];
        float score = __uint_as_float((unsigned)(key >> 32));
        unsigned n = 0xFFFFFFFFu - (unsigned)(key & 0xFFFFFFFFull);
        if (n >= NANCH) n = 0;     // safety only; count >= 300 always
        const float* rec = logits + ((size_t)b * NANCH + n) * REC;
        float cx = rec[0], cy = rec[1], w = rec[2], h = rec[3];
        float bestv = rec[5]; int lab = 0;
        for (int c = 1; c < NCLS; ++c) {
            float v = rec[5 + c];
            if (v > bestv) { bestv = v; lab = c; }   // first-max, matches argmax
        }
        float hw = opaque_f(w * 0.5f);   // block FMA contraction -> match XLA rounding
        float hh = opaque_f(h * 0.5f);
        float x1 = cx - hw, y1 = cy - hh, x2 = cx + hw, y2 = cy + hh;
        bx1[tid] = x1; by1[tid] = y1; bx2[tid] = x2; by2[tid] = y2;
        size_t o = (size_t)(b * MAXDET + tid);
        out[OFF_PB + o * 4 + 0] = x1;
        out[OFF_PB + o * 4 + 1] = y1;
        out[OFF_PB + o * 4 + 2] = x2;
        out[OFF_PB + o * 4 + 3] = y2;
        out[OFF_PS + o] = score;
        out[OFF_PL + o] = (float)lab;
    }
    if (tid < 10) keepw[tid] = (tid < 9) ? 0xFFFFFFFFu : 0xFFFu;  // 300 valid bits
    __syncthreads();
    // suppression matrix, parallel over pairs
    for (int p = tid; p < MAXDET * MAXDET; p += 512) {
        int i = p / MAXDET;
        int j = p - i * MAXDET;
        if (j > i) {
            float ai = (bx2[i] - bx1[i]) * (by2[i] - by1[i]);
            float aj = (bx2[j] - bx1[j]) * (by2[j] - by1[j]);
            float ltx = fmaxf(bx1[i], bx1[j]);
            float lty = fmaxf(by1[i], by1[j]);
            float rbx = fminf(bx2[i], bx2[j]);
            float rby = fminf(by2[i], by2[j]);
            float wx = fmaxf(rbx - ltx, 0.0f);
            float wy = fmaxf(rby - lty, 0.0f);
            float inter = wx * wy;
            float iou = inter / (ai + aj - inter + 1e-9f);  // left-to-right adds, no fma
            if (iou > 0.4f) atomicOr(&supp[i * 10 + (j >> 5)], 1u << (j & 31));
        }
    }
    __syncthreads();
    // sequential greedy scan: one wave, lane q owns keep word q, prefetch supp rows
    if (tid < 64) {
        int q = tid;
        unsigned kw = (q < 10) ? keepw[q] : 0u;
        unsigned nextrow = (q < 10) ? supp[q] : 0u;   // row 0
        for (int i = 0; i < MAXDET; ++i) {
            unsigned rowq = nextrow;
            if (q < 10 && i + 1 < MAXDET) nextrow = supp[(i + 1) * 10 + q];
            unsigned wown = __shfl(kw, i >> 5);        // uniform broadcast
            if ((wown >> (i & 31)) & 1u) kw &= ~rowq;  // rows only contain j>i bits
        }
        if (q < 10) keepw[q] = kw;
    }
    __syncthreads();
    if (tid < MAXDET)
        out[OFF_PK + (size_t)b * MAXDET + tid] =
            ((keepw[tid >> 5] >> (tid & 31)) & 1u) ? 1.0f : 0.0f;
}

// ---------------- Kernel D: targets ----------------
__global__ __launch_bounds__(64) void kD(const float* __restrict__ targets,
                                         const int* __restrict__ tlen,
                                         float* __restrict__ out) {
    int b = blockIdx.x, t = threadIdx.x;
    if (t >= TMAX) return;
    // int64-vs-int32 layout autodetect (lengths are in [1,49], never 0)
    bool is64 = (tlen[1] == 0) && (tlen[3] == 0) && (tlen[5] == 0);
    int len = is64 ? tlen[2 * b] : tlen[b];
    const float* r = targets + ((size_t)b * TMAX + t) * 6;
    float cx = r[0], cy = r[1], w = r[2], h = r[3], sc = r[4], lb = r[5];
    float hw = opaque_f(w * 0.5f);
    float hh = opaque_f(h * 0.5f);
    size_t o = (size_t)b * TMAX + t;
    out[OFF_TB + o * 4 + 0] = cx - hw;
    out[OFF_TB + o * 4 + 1] = cy - hh;
    out[OFF_TB + o * 4 + 2] = cx + hw;
    out[OFF_TB + o * 4 + 3] = cy + hh;
    out[OFF_TS + o] = sc;
    out[OFF_TL + o] = (float)(int)lb;
    out[OFF_TV + o] = (t < len) ? 1.0f : 0.0f;
}

extern "C" void kernel_launch(void* const* d_in, const int* in_sizes, int n_in,
                              void* d_out, int out_size, void* d_ws, size_t ws_size,
                              hipStream_t stream) {
    const float* logits  = (const float*)d_in[0];
    const float* targets = (const float*)d_in[1];
    const int*   tlen    = (const int*)d_in[2];
    float* out = (float*)d_out;
    char* ws = (char*)d_ws;
    int* cnt = (int*)ws;                                           // 16 x 64B
    unsigned long long* keys = (unsigned long long*)(ws + 1024);   // 16 x 8192 x u64
    unsigned long long* topk = (unsigned long long*)(ws + 1024 + (size_t)BATCH * CAP * 8);

    hipMemsetAsync(cnt, 0, 1024, stream);
    hipLaunchKernelGGL(kA, dim3((BATCH * NANCH) / 128), dim3(128), 0, stream, logits, cnt, keys);
    hipLaunchKernelGGL(kB, dim3(BATCH), dim3(1024), 0, stream, cnt, keys, topk);
    hipLaunchKernelGGL(kC, dim3(BATCH), dim3(512), 0, stream, logits, topk, out);
    hipLaunchKernelGGL(kD, dim3(BATCH), dim3(64), 0, stream, targets, tlen, out);
}

// Round 2
// 417.181 us; speedup vs baseline: 1.0540x; 1.0540x over previous
//
#include <hip/hip_runtime.h>
#include <stdint.h>

#define BATCH   16
#define NANCH   25200
#define NCLS    80
#define REC     85
#define MAXDET  300
#define TMAX    50
#define CAP     8192
#define NBUCKET 2048
#define FINCAP  1024

// output offsets (floats)
#define OFF_PB 0
#define OFF_PS 19200
#define OFF_PL 24000
#define OFF_PK 28800
#define OFF_TB 33600
#define OFF_TS 36800
#define OFF_TL 37600
#define OFF_TV 38400

__device__ __forceinline__ float opaque_f(float x) { asm volatile("" : "+v"(x)); return x; }

// ---------------- Kernel A: score + compact candidates ----------------
// No LDS, no barriers: each thread owns one anchor, 21 independent loads in
// flight. Wave footprint = 64*340B contiguous -> full cache-line consumption.
__global__ __launch_bounds__(256) void kA(const float* __restrict__ logits,
                                          int* __restrict__ cnt,
                                          unsigned long long* __restrict__ keys) {
    const int g = blockIdx.x * 256 + threadIdx.x;
    if (g >= BATCH * NANCH) return;
    const float* rec = logits + (size_t)g * REC;
    const float obj = rec[4];
    const float4* c4 = (const float4*)(rec + 5);   // dword-aligned; HW ok
    float m0 = -1.0f, m1 = -1.0f, m2 = -1.0f, m3 = -1.0f;
#pragma unroll
    for (int i = 0; i < 20; ++i) {
        float4 v = c4[i];
        m0 = fmaxf(m0, v.x); m1 = fmaxf(m1, v.y);
        m2 = fmaxf(m2, v.z); m3 = fmaxf(m3, v.w);
    }
    const float best = fmaxf(fmaxf(m0, m1), fmaxf(m2, m3));
    const float conf = obj * best;                 // exact: single multiply
    if (conf > 0.8f) {
        int b = g / NANCH;
        int n = g - b * NANCH;
        int pos = atomicAdd(cnt + b * 16, 1);      // counters padded to 64B
        if (pos < CAP) {
            unsigned long long key =
                ((unsigned long long)__float_as_uint(conf) << 32) |
                (unsigned)(0xFFFFFFFFu - (unsigned)n);   // ties: smaller idx first
            keys[(size_t)b * CAP + pos] = key;
        }
    }
}

// ---------------- Kernel B: radix-select + bitonic top-300 ----------------
__global__ __launch_bounds__(1024) void kB(const int* __restrict__ cnt,
                                           const unsigned long long* __restrict__ keys,
                                           unsigned long long* __restrict__ topkeys) {
    __shared__ unsigned hist[NBUCKET];
    __shared__ unsigned long long fin[FINCAP];
    __shared__ int sTb, sCnt;
    const int b = blockIdx.x;
    const int tid = threadIdx.x;
    int cb = cnt[b * 16]; if (cb > CAP) cb = CAP;
    const unsigned long long* kb = keys + (size_t)b * CAP;

    for (int i = tid; i < NBUCKET; i += 1024) hist[i] = 0u;
    if (tid == 0) sCnt = 0;
    __syncthreads();
    for (int i = tid; i < cb; i += 1024) {
        unsigned bits = (unsigned)(kb[i] >> 32);      // conf bits, > 0x3F4CCCCD
        unsigned bk = (bits - 0x3F4CCCCDu) >> 11;     // linear in value (one binade)
        if (bk > NBUCKET - 1u) bk = NBUCKET - 1u;
        atomicAdd(&hist[bk], 1u);
    }
    __syncthreads();
    if (tid == 0) {
        int c = 0, tb = 0;
        for (int bk = NBUCKET - 1; bk >= 0; --bk) {
            c += (int)hist[bk];
            if (c >= MAXDET) { tb = bk; break; }
        }
        sTb = tb;
    }
    __syncthreads();
    int tb = sTb;
    for (int i = tid; i < cb; i += 1024) {
        unsigned long long k = kb[i];
        unsigned bits = (unsigned)(k >> 32);
        unsigned bk = (bits - 0x3F4CCCCDu) >> 11;
        if (bk > NBUCKET - 1u) bk = NBUCKET - 1u;
        if ((int)bk >= tb) {
            int p = atomicAdd(&sCnt, 1);
            if (p < FINCAP) fin[p] = k;
        }
    }
    __syncthreads();
    int fc = sCnt; if (fc > FINCAP) fc = FINCAP;
    for (int i = tid; i < FINCAP; i += 1024) if (i >= fc) fin[i] = 0ull;
    // bitonic sort descending (keys unique -> deterministic)
    for (unsigned k = 2; k <= FINCAP; k <<= 1) {
        for (unsigned j = k >> 1; j > 0; j >>= 1) {
            __syncthreads();
            unsigned t = tid;
            unsigned ixj = t ^ j;
            if (ixj > t && t < FINCAP) {
                unsigned long long a = fin[t], c2 = fin[ixj];
                bool desc = ((t & k) == 0u);
                bool sw = desc ? (a < c2) : (a > c2);
                if (sw) { fin[t] = c2; fin[ixj] = a; }
            }
        }
    }
    __syncthreads();
    if (tid < MAXDET) topkeys[b * MAXDET + tid] = fin[tid];
}

// ---------------- Kernel C: gather + NMS + outputs ----------------
__global__ __launch_bounds__(512) void kC(const float* __restrict__ logits,
                                          const unsigned long long* __restrict__ topkeys,
                                          float* __restrict__ out) {
    __shared__ float bx1[MAXDET], by1[MAXDET], bx2[MAXDET], by2[MAXDET];
    __shared__ unsigned supp[MAXDET * 10];   // 300 rows x 320 bits
    __shared__ unsigned keepw[10];
    const int b = blockIdx.x;
    const int tid = threadIdx.x;
    for (int i = tid; i < MAXDET * 10; i += 512) supp[i] = 0u;
    if (tid < MAXDET) {
        unsigned long long key = topkeys[b * MAXDET + tid];
        float score = __uint_as_float((unsigned)(key >> 32));
        unsigned n = 0xFFFFFFFFu - (unsigned)(key & 0xFFFFFFFFull);
        if (n >= NANCH) n = 0;     // safety only; count >= 300 always
        const float* rec = logits + ((size_t)b * NANCH + n) * REC;
        float cx = rec[0], cy = rec[1], w = rec[2], h = rec[3];
        float bestv = rec[5]; int lab = 0;
        for (int c = 1; c < NCLS; ++c) {
            float v = rec[5 + c];
            if (v > bestv) { bestv = v; lab = c; }   // first-max, matches argmax
        }
        float hw = opaque_f(w * 0.5f);   // block FMA contraction -> match XLA rounding
        float hh = opaque_f(h * 0.5f);
        float x1 = cx - hw, y1 = cy - hh, x2 = cx + hw, y2 = cy + hh;
        bx1[tid] = x1; by1[tid] = y1; bx2[tid] = x2; by2[tid] = y2;
        size_t o = (size_t)(b * MAXDET + tid);
        out[OFF_PB + o * 4 + 0] = x1;
        out[OFF_PB + o * 4 + 1] = y1;
        out[OFF_PB + o * 4 + 2] = x2;
        out[OFF_PB + o * 4 + 3] = y2;
        out[OFF_PS + o] = score;
        out[OFF_PL + o] = (float)lab;
    }
    if (tid < 10) keepw[tid] = (tid < 9) ? 0xFFFFFFFFu : 0xFFFu;  // 300 valid bits
    __syncthreads();
    // suppression matrix, parallel over pairs
    for (int p = tid; p < MAXDET * MAXDET; p += 512) {
        int i = p / MAXDET;
        int j = p - i * MAXDET;
        if (j > i) {
            float ai = (bx2[i] - bx1[i]) * (by2[i] - by1[i]);
            float aj = (bx2[j] - bx1[j]) * (by2[j] - by1[j]);
            float ltx = fmaxf(bx1[i], bx1[j]);
            float lty = fmaxf(by1[i], by1[j]);
            float rbx = fminf(bx2[i], bx2[j]);
            float rby = fminf(by2[i], by2[j]);
            float wx = fmaxf(rbx - ltx, 0.0f);
            float wy = fmaxf(rby - lty, 0.0f);
            float inter = wx * wy;
            float iou = inter / (ai + aj - inter + 1e-9f);  // left-to-right adds, no fma
            if (iou > 0.4f) atomicOr(&supp[i * 10 + (j >> 5)], 1u << (j & 31));
        }
    }
    __syncthreads();
    // sequential greedy scan: one wave, lane q owns keep word q, prefetch supp rows
    if (tid < 64) {
        int q = tid;
        unsigned kw = (q < 10) ? keepw[q] : 0u;
        unsigned nextrow = (q < 10) ? supp[q] : 0u;   // row 0
        for (int i = 0; i < MAXDET; ++i) {
            unsigned rowq = nextrow;
            if (q < 10 && i + 1 < MAXDET) nextrow = supp[(i + 1) * 10 + q];
            unsigned wown = __shfl(kw, i >> 5);        // uniform broadcast
            if ((wown >> (i & 31)) & 1u) kw &= ~rowq;  // rows only contain j>i bits
        }
        if (q < 10) keepw[q] = kw;
    }
    __syncthreads();
    if (tid < MAXDET)
        out[OFF_PK + (size_t)b * MAXDET + tid] =
            ((keepw[tid >> 5] >> (tid & 31)) & 1u) ? 1.0f : 0.0f;
}

// ---------------- Kernel D: targets ----------------
__global__ __launch_bounds__(64) void kD(const float* __restrict__ targets,
                                         const int* __restrict__ tlen,
                                         float* __restrict__ out) {
    int b = blockIdx.x, t = threadIdx.x;
    if (t >= TMAX) return;
    // int64-vs-int32 layout autodetect (lengths are in [1,49], never 0)
    bool is64 = (tlen[1] == 0) && (tlen[3] == 0) && (tlen[5] == 0);
    int len = is64 ? tlen[2 * b] : tlen[b];
    const float* r = targets + ((size_t)b * TMAX + t) * 6;
    float cx = r[0], cy = r[1], w = r[2], h = r[3], sc = r[4], lb = r[5];
    float hw = opaque_f(w * 0.5f);
    float hh = opaque_f(h * 0.5f);
    size_t o = (size_t)b * TMAX + t;
    out[OFF_TB + o * 4 + 0] = cx - hw;
    out[OFF_TB + o * 4 + 1] = cy - hh;
    out[OFF_TB + o * 4 + 2] = cx + hw;
    out[OFF_TB + o * 4 + 3] = cy + hh;
    out[OFF_TS + o] = sc;
    out[OFF_TL + o] = (float)(int)lb;
    out[OFF_TV + o] = (t < len) ? 1.0f : 0.0f;
}

extern "C" void kernel_launch(void* const* d_in, const int* in_sizes, int n_in,
                              void* d_out, int out_size, void* d_ws, size_t ws_size,
                              hipStream_t stream) {
    const float* logits  = (const float*)d_in[0];
    const float* targets = (const float*)d_in[1];
    const int*   tlen    = (const int*)d_in[2];
    float* out = (float*)d_out;
    char* ws = (char*)d_ws;
    int* cnt = (int*)ws;                                           // 16 x 64B
    unsigned long long* keys = (unsigned long long*)(ws + 1024);   // 16 x 8192 x u64
    unsigned long long* topk = (unsigned long long*)(ws + 1024 + (size_t)BATCH * CAP * 8);

    hipMemsetAsync(cnt, 0, 1024, stream);
    hipLaunchKernelGGL(kA, dim3((BATCH * NANCH + 255) / 256), dim3(256), 0, stream, logits, cnt, keys);
    hipLaunchKernelGGL(kB, dim3(BATCH), dim3(1024), 0, stream, cnt, keys, topk);
    hipLaunchKernelGGL(kC, dim3(BATCH), dim3(512), 0, stream, logits, topk, out);
    hipLaunchKernelGGL(kD, dim3(BATCH), dim3(64), 0, stream, targets, tlen, out);
}